// Round 20
// baseline (404.252 us; speedup 1.0000x reference)
//
#include <hip/hip_runtime.h>
#include <hip/hip_bf16.h>
#include <cmath>

#define HW      32400
#define WIMG    180
#define DD      128
#define NHEADS  8
#define DHEAD   16
#define LTOK    225
#define PSTRIDE 64928            // 32400 + slack per batch
#define FBROW   188
#define FBH     182
#define FBSZ    ((size_t)FBH * FBROW * 128)   // padded pixel-major conv input per batch
#define QSCALE  0.36067376022224085f          // log2(e)/4, folded into q projection

typedef __attribute__((ext_vector_type(8))) short bf16x8;
typedef __attribute__((ext_vector_type(4))) short bf16x4;
typedef __attribute__((ext_vector_type(4))) float f32x4;

union U16B { uint4 u; int4 i; bf16x8 v; };
union U8B  { uint2 u; bf16x4 v; };

__device__ __forceinline__ bf16x8 ldfrag(const __hip_bfloat16* p, int ld, int lane) {
  // fragment for mfma_f32_16x16x32_bf16: row = lane&15 (stride ld), k = (lane>>4)*8..+7 contiguous
  return *(const bf16x8*)(p + (size_t)(lane & 15) * ld + ((lane >> 4) << 3));
}

__device__ __forceinline__ float bf2f(unsigned int u) {
  return __uint_as_float(u << 16);
}

__device__ __forceinline__ unsigned short f2bf(float x) {
  unsigned int b = __float_as_uint(x);
  return (unsigned short)((b + 0x7fffu + ((b >> 16) & 1u)) >> 16);
}

// ---------------------------------------------------------------------------
// weight prep (all 5 preps fused into one launch)
// ---------------------------------------------------------------------------
__global__ void k_prep_all(
    const float* __restrict__ ipw, const float* __restrict__ opw,
    const float* __restrict__ ocw, const float* __restrict__ cam_w,
    const float* __restrict__ lid_w,
    __hip_bfloat16* __restrict__ wipb, __hip_bfloat16* __restrict__ wob,
    __hip_bfloat16* __restrict__ wcb, __hip_bfloat16* __restrict__ wcamb,
    __hip_bfloat16* __restrict__ wlidb) {
  int i = blockIdx.x * 256 + threadIdx.x;
  if (i < 49152) { wipb[i] = __float2bfloat16(ipw[i]); return; }
  i -= 49152;
  if (i < 16384) { wob[i] = __float2bfloat16(opw[i]); return; }
  i -= 16384;
  if (i < 294912) {
    // conv weights -> frag-major: [oc16(16)][tap(9)][chunk(4)][lane(64)][e(8)]
    int oc16  = i / 18432;
    int r0    = i % 18432;
    int tap   = r0 / 2048;
    int r1    = r0 % 2048;
    int chunk = r1 / 512;
    int r2    = r1 % 512;
    int lane  = r2 / 8;
    int e     = r2 % 8;
    int oc = oc16 * 16 + (lane & 15);
    int ic = chunk * 32 + (lane >> 4) * 8 + e;
    wcb[i] = __float2bfloat16(ocw[(size_t)(oc * 128 + ic) * 9 + tap]);
    return;
  }
  i -= 294912;
  if (i < 16384) {           // cam proj weights, C=80 zero-padded to Kpad=128
    int d = i / 128, c = i % 128;
    wcamb[i] = (c < 80) ? __float2bfloat16(cam_w[d * 80 + c]) : __float2bfloat16(0.f);
    return;
  }
  i -= 16384;
  if (i < 32768) { wlidb[i] = __float2bfloat16(lid_w[i]); return; }  // C==Kpad==256
}

// ---------------------------------------------------------------------------
// 1) 1x1 conv + BN + ReLU as implicit MFMA GEMM
// ---------------------------------------------------------------------------
__global__ void __launch_bounds__(256) k_proj_mfma(
    const float* __restrict__ in, const __hip_bfloat16* __restrict__ wb,
    const float* __restrict__ g, const float* __restrict__ be,
    const float* __restrict__ mu, const float* __restrict__ var,
    __hip_bfloat16* __restrict__ outp, int C, int Kpad) {
  __shared__ __align__(16) __hip_bfloat16 sa[128 * 64];
  int m0 = blockIdx.x * 128;
  int b = blockIdx.z;
  int tid = threadIdx.x, lane = tid & 63, wid = tid >> 6;
  int wm = (wid >> 1) * 64, wn = (wid & 1) * 64;
  const float* inb = in + (size_t)b * C * HW;
  int sp = (tid >> 1) & 127;
  int sc4 = (tid & 1) * 4;
  int gp = m0 + sp;
  bool pok = gp < HW;
  f32x4 acc[4][4] = {};
  for (int kc = 0; kc < Kpad; kc += 64) {
    __syncthreads();
#pragma unroll
    for (int it = 0; it < 8; ++it) {
      int lc = sc4 + it * 8;
      int c = kc + lc;
      unsigned short u[4];
#pragma unroll
      for (int j = 0; j < 4; ++j) {
        float x = (pok && (c + j) < C) ? inb[(size_t)(c + j) * HW + gp] : 0.f;
        u[j] = f2bf(x);
      }
      int blk = (lc >> 3) ^ (sp & 7);
      char* dst = (char*)sa + sp * 128 + blk * 16 + (lc & 7) * 2;
      *(uint2*)dst = make_uint2(((unsigned)u[1] << 16) | u[0],
                                ((unsigned)u[3] << 16) | u[2]);
    }
    __syncthreads();
#pragma unroll
    for (int ks = 0; ks < 2; ++ks) {
      bf16x8 af[4], bfr[4];
#pragma unroll
      for (int i = 0; i < 4; ++i) {
        int pr = wm + i * 16 + (lane & 15);
        int blk = ((ks * 4 + (lane >> 4)) ^ (pr & 7));
        af[i] = *(const bf16x8*)((const char*)sa + pr * 128 + blk * 16);
      }
#pragma unroll
      for (int j = 0; j < 4; ++j)
        bfr[j] = ldfrag(wb + (size_t)(wn + j * 16) * Kpad + kc + ks * 32, Kpad, lane);
#pragma unroll
      for (int i = 0; i < 4; ++i)
#pragma unroll
        for (int j = 0; j < 4; ++j)
          acc[i][j] = __builtin_amdgcn_mfma_f32_16x16x32_bf16(af[i], bfr[j], acc[i][j], 0, 0, 0);
    }
  }
  int col = lane & 15, rq = lane >> 4;
  __hip_bfloat16* ob = outp + (size_t)b * PSTRIDE * 128;
#pragma unroll
  for (int j = 0; j < 4; ++j) {
    int d = wn + j * 16 + col;
    float s = g[d] * rsqrtf(var[d] + 1e-5f);
    float mm = mu[d], bb = be[d];
#pragma unroll
    for (int i = 0; i < 4; ++i) {
#pragma unroll
      for (int r = 0; r < 4; ++r) {
        int m = m0 + wm + i * 16 + rq * 4 + r;
        if (m < HW) {
          float y = (acc[i][j][r] - mm) * s + bb;
          ob[(size_t)m * 128 + d] = __float2bfloat16(fmaxf(y, 0.f));
        }
      }
    }
  }
}

// ---------------------------------------------------------------------------
// 2) MFMA GEMM with bias and output scale
// ---------------------------------------------------------------------------
__global__ void __launch_bounds__(256) k_gemm_bias(
    const __hip_bfloat16* __restrict__ A, const __hip_bfloat16* __restrict__ B,
    const float* __restrict__ bias, __hip_bfloat16* __restrict__ out,
    int K, int ldout, float oscale) {
  int m0 = blockIdx.x * 128, n0 = blockIdx.y * 128, b = blockIdx.z;
  int lane = threadIdx.x & 63, wid = threadIdx.x >> 6;
  int wm = (wid >> 1) * 64, wn = (wid & 1) * 64;
  const __hip_bfloat16* Ab = A + (size_t)b * PSTRIDE * K;
  f32x4 acc[4][4] = {};
  for (int kc = 0; kc < K; kc += 32) {
    bf16x8 af[4], bfr[4];
#pragma unroll
    for (int i = 0; i < 4; ++i)
      af[i] = ldfrag(Ab + (size_t)(m0 + wm + i * 16) * K + kc, K, lane);
#pragma unroll
    for (int j = 0; j < 4; ++j)
      bfr[j] = ldfrag(B + (size_t)(n0 + wn + j * 16) * K + kc, K, lane);
#pragma unroll
    for (int i = 0; i < 4; ++i)
#pragma unroll
      for (int j = 0; j < 4; ++j)
        acc[i][j] = __builtin_amdgcn_mfma_f32_16x16x32_bf16(af[i], bfr[j], acc[i][j], 0, 0, 0);
  }
  int col = lane & 15, rq = lane >> 4;
  __hip_bfloat16* ob = out + (size_t)b * PSTRIDE * ldout;
#pragma unroll
  for (int j = 0; j < 4; ++j) {
    int n = n0 + wn + j * 16 + col;
    float bs = bias[n];
#pragma unroll
    for (int i = 0; i < 4; ++i) {
#pragma unroll
      for (int r = 0; r < 4; ++r) {
        int m = m0 + wm + i * 16 + rq * 4 + r;
        if (m < HW) ob[(size_t)m * ldout + n] = __float2bfloat16((acc[i][j][r] + bs) * oscale);
      }
    }
  }
}

// ---------------------------------------------------------------------------
// 3) MFMA flash attention per (bn, head) — 16x16x16 MFMA, P stays in regs.
//    Also absorbs the fb-border zeroing (fbbuf disjoint from qc/kvb).
// ---------------------------------------------------------------------------
__global__ void __launch_bounds__(256) k_attn_mfma(
    const __hip_bfloat16* __restrict__ qc, const __hip_bfloat16* __restrict__ kvb,
    __hip_bfloat16* __restrict__ ctx, __hip_bfloat16* __restrict__ fbb) {
  __shared__ __align__(8) uint2 Kf[15 * 64];   // frag-major K: lane(g,q)=K[key q][d g*4..+3]
  __shared__ __align__(8) uint2 Vf[15 * 64];   // frag-major V^T: lane(g,q)=V^T[d q][key g*4..+3]
  int bn = blockIdx.x, hh = blockIdx.y;
  int b = bn / 144, rr = bn % 144, tby = rr / 12, tbx = rr % 12;
  int tid = threadIdx.x;
  int pbase = tby * 15 * WIMG + tbx * 15;
  const __hip_bfloat16* kvbase = kvb + (size_t)b * PSTRIDE * 256 + hh * 16;

  // ---- absorbed fb border zeroing (92*256 = 23552 items exactly) ----
  if (hh == 0 && bn < 92) {
    int idx = bn * 256 + tid;
    int zb = idx / (736 * 16);
    int r = idx % (736 * 16);
    int px = r >> 4, blk = r & 15;
    int row, col;
    if (px < 188)      { row = 0;            col = px; }
    else if (px < 376) { row = 181;          col = px - 188; }
    else if (px < 556) { row = px - 376 + 1; col = 0; }
    else               { row = px - 556 + 1; col = 181; }
    ((uint4*)(fbb + (size_t)zb * FBSZ + ((size_t)row * FBROW + col) * 128))[blk] =
        make_uint4(0u, 0u, 0u, 0u);
  }

  // ---- stage K and V^T into frag-major layout ----
  if (tid < 240) {
    int row = tid;
    int ck = row >> 4, q = row & 15;
    uint4 k0 = make_uint4(0, 0, 0, 0), k1 = k0, v0 = k0, v1 = k0;
    if (row < LTOK) {
      int p = pbase + (row / 15) * WIMG + (row % 15);
      const uint4* kp = (const uint4*)(kvbase + (size_t)p * 256);
      k0 = kp[0]; k1 = kp[1];
      v0 = kp[16]; v1 = kp[17];     // V at +128 elements
    }
    Kf[ck * 64 + q]      = make_uint2(k0.x, k0.y);
    Kf[ck * 64 + 16 + q] = make_uint2(k0.z, k0.w);
    Kf[ck * 64 + 32 + q] = make_uint2(k1.x, k1.y);
    Kf[ck * 64 + 48 + q] = make_uint2(k1.z, k1.w);
    unsigned short vv[16];
    *(uint4*)&vv[0] = v0;
    *(uint4*)&vv[8] = v1;
    int vg = q >> 2, vj = q & 3;
    unsigned short* vb = (unsigned short*)&Vf[ck * 64 + vg * 16];
#pragma unroll
    for (int d0 = 0; d0 < 16; ++d0) {
      int d = (d0 + q) & 15;
      vb[d * 4 + vj] = vv[d];
    }
  }
  __syncthreads();

  int lane = tid & 63, wid = tid >> 6;
  int g = lane >> 4, q15 = lane & 15;
  int wq0 = wid * 64;
  const uint2* KfB = Kf + lane;
  const uint2* VfB = Vf + lane;

  // Q fragments: lane(g,q15) = Q[query q15][d g*4..+3] — full dh, no padding
  bf16x4 qf[4];
#pragma unroll
  for (int i = 0; i < 4; ++i) {
    int q = wq0 + i * 16 + q15;
    int qq = q < LTOK ? q : 0;
    int p = pbase + (qq / 15) * WIMG + (qq % 15);
    U8B u;
    u.u = *(const uint2*)(qc + ((size_t)b * PSTRIDE + p) * 128 + hh * 16 + g * 4);
    qf[i] = u.v;
  }

  float ls[4] = {0.f, 0.f, 0.f, 0.f};
  f32x4 oac[4] = {};
#pragma unroll 1
  for (int ck = 0; ck < 15; ++ck) {
    U8B ku; ku.u = KfB[ck * 64];
    U8B vu; vu.u = VfB[ck * 64];
    bf16x4 kf = ku.v, vf = vu.v;
#pragma unroll
    for (int i = 0; i < 4; ++i) {
      f32x4 st = {0.f, 0.f, 0.f, 0.f};
      asm("v_mfma_f32_16x16x16_bf16 %0, %1, %2, %0" : "+v"(st) : "v"(kf), "v"(qf[i]));
      float p0 = exp2f(st[0]);
      float p1 = exp2f(st[1]);
      float p2 = exp2f(st[2]);
      float p3 = exp2f(st[3]);
      if (ck == 14) {                  // keys 224..239: only key 224 (g=0,r=0) valid
        if (g) p0 = 0.f;
        p1 = 0.f; p2 = 0.f; p3 = 0.f;
      }
      ls[i] += (p0 + p1) + (p2 + p3);
      U8B pu;
      pu.u = make_uint2((unsigned)f2bf(p0) | ((unsigned)f2bf(p1) << 16),
                        (unsigned)f2bf(p2) | ((unsigned)f2bf(p3) << 16));
      asm("v_mfma_f32_16x16x16_bf16 %0, %1, %2, %0" : "+v"(oac[i]) : "v"(vf), "v"(pu.v));
    }
  }
#pragma unroll
  for (int i = 0; i < 4; ++i) {
    ls[i] += __shfl_xor(ls[i], 16);
    ls[i] += __shfl_xor(ls[i], 32);
  }

  // ---- epilogue: normalize and store (lane owns ctx[q][hh*16 + g*4 .. +3]) ----
  __hip_bfloat16* cb = ctx + (size_t)b * PSTRIDE * 128 + hh * 16;
#pragma unroll
  for (int i = 0; i < 4; ++i) {
    float inv = 1.f / ls[i];
    int qo = wq0 + i * 16 + q15;
    if (qo < LTOK) {
      unsigned lo = (unsigned)f2bf(oac[i][0] * inv) | ((unsigned)f2bf(oac[i][1] * inv) << 16);
      unsigned hi = (unsigned)f2bf(oac[i][2] * inv) | ((unsigned)f2bf(oac[i][3] * inv) << 16);
      int p = pbase + (qo / 15) * WIMG + (qo % 15);
      *(uint2*)(cb + (size_t)p * 128 + g * 4) = make_uint2(lo, hi);
    }
  }
}

// ---------------------------------------------------------------------------
// 4) out-proj MFMA GEMM + bias + residual -> padded fb bf16
// ---------------------------------------------------------------------------
__global__ void __launch_bounds__(256) k_outproj_mfma(
    const __hip_bfloat16* __restrict__ ctx, const __hip_bfloat16* __restrict__ wob,
    const float* __restrict__ opb, const __hip_bfloat16* __restrict__ lidb,
    __hip_bfloat16* __restrict__ fb) {
  int m0 = blockIdx.x * 128, b = blockIdx.z;
  int lane = threadIdx.x & 63, wid = threadIdx.x >> 6;
  int wm = (wid >> 1) * 64, wn = (wid & 1) * 64;
  const __hip_bfloat16* Ab = ctx + (size_t)b * PSTRIDE * 128;
  f32x4 acc[4][4] = {};
  for (int kc = 0; kc < 128; kc += 32) {
    bf16x8 af[4], bfr[4];
#pragma unroll
    for (int i = 0; i < 4; ++i)
      af[i] = ldfrag(Ab + (size_t)(m0 + wm + i * 16) * 128 + kc, 128, lane);
#pragma unroll
    for (int j = 0; j < 4; ++j)
      bfr[j] = ldfrag(wob + (size_t)(wn + j * 16) * 128 + kc, 128, lane);
#pragma unroll
    for (int i = 0; i < 4; ++i)
#pragma unroll
      for (int j = 0; j < 4; ++j)
        acc[i][j] = __builtin_amdgcn_mfma_f32_16x16x32_bf16(af[i], bfr[j], acc[i][j], 0, 0, 0);
  }
  int col = lane & 15, rq = lane >> 4;
  const __hip_bfloat16* lb = lidb + (size_t)b * PSTRIDE * 128;
  __hip_bfloat16* fbp = fb + (size_t)b * FBSZ;
#pragma unroll
  for (int j = 0; j < 4; ++j) {
    int n = wn + j * 16 + col;
    float bs = opb[n];
#pragma unroll
    for (int i = 0; i < 4; ++i) {
#pragma unroll
      for (int r = 0; r < 4; ++r) {
        int m = m0 + wm + i * 16 + rq * 4 + r;
        if (m < HW) {
          float v = acc[i][j][r] + bs + __bfloat162float(lb[(size_t)m * 128 + n]);
          int hhh = m / WIMG, www = m % WIMG;
          fbp[((size_t)(hhh + 1) * FBROW + (www + 1)) * 128 + n] = __float2bfloat16(v);
        }
      }
    }
  }
}

// ---------------------------------------------------------------------------
// 5) 3x3 conv 128->256 + BN + ReLU: 2 rows x 60 px x 256 oc per block,
//    ic-halved LDS A staging (row stride 63), 3-deep B register prefetch.
//    NEW: (a) __launch_bounds__(512,4) -> VGPR<=128 for 2-block residency
//    (est. usage ~120, no spill); (b) T14 async half-1 A staging: global
//    loads issued before half-0 compute, ds_write at the boundary.
// ---------------------------------------------------------------------------
__global__ void __launch_bounds__(512, 4) k_conv_mfma(
    const __hip_bfloat16* __restrict__ fb, const __hip_bfloat16* __restrict__ wcb,
    const float* __restrict__ g, const float* __restrict__ be,
    const float* __restrict__ mu, const float* __restrict__ var,
    float* __restrict__ out) {
  __shared__ __align__(16) uint4 Asm[32 * 63];   // [dy(4)*8+kgrp8][px], row stride 63
  int bx = blockIdx.x;                 // 0..269: hpair*3 + strip
  int hp = bx / 3, strip = bx % 3;
  int h0 = hp * 2;                     // output rows h0, h0+1
  int w0 = strip * 60;
  int b = blockIdx.z;
  int tid = threadIdx.x, lane = tid & 63, wid = tid >> 6;   // wid 0..7
  int q15 = lane & 15, kg = lane >> 4;
  int wpx = (wid & 1) * 32;            // pixel half
  int ocq = wid >> 1;                  // oc quarter (0..3)
  const __hip_bfloat16* fbb = fb + (size_t)b * FBSZ;
  const __hip_bfloat16* Bw = wcb + (size_t)(ocq * 4) * 18432 + lane * 8;

#define STAGEA(half)                                                           \
  {                                                                            \
    _Pragma("unroll") for (int it = 0; it < 4; ++it) {                         \
      int slot = it * 512 + tid;                                               \
      if (slot < 1984) {                                                       \
        int px = slot % 62;                                                    \
        int rowk = slot / 62;          /* dy*8 + k8 */                         \
        int dy = rowk >> 3, k8 = rowk & 7;                                     \
        Asm[rowk * 63 + px] = *(const uint4*)(fbb + ((size_t)(h0 + dy) * FBROW + (w0 + px)) * 128 + ((half) * 8 + k8) * 8); \
      }                                                                        \
    }                                                                          \
  }

// half-1 slot -> global address (same indexing as STAGEA(1))
#define A1SRC(slot)                                                            \
  (*(const uint4*)(fbb + ((size_t)(h0 + (((slot) / 62) >> 3)) * FBROW + (w0 + (slot) % 62)) * 128 + (8 + (((slot) / 62) & 7)) * 8))

// global step s (0..35): half = s/18, tap = (s%18)/2, ch2 = s&1
#define LOADB(dst, s)                                                          \
  {                                                                            \
    int half_ = (s) / 18, rem_ = (s) % 18, tap_ = rem_ / 2, ch2_ = rem_ & 1;   \
    int chunk_ = half_ * 2 + ch2_;                                             \
    _Pragma("unroll") for (int j = 0; j < 4; ++j)                              \
        dst[j] = *(const bf16x8*)(Bw + (size_t)j * 18432 + tap_ * 2048 + chunk_ * 512); \
  }

#define LOADBG(dst, s)                                                         \
  { if ((s) < 36) LOADB(dst, s); }

#define STEP(s, bp)                                                            \
  {                                                                            \
    int rem_ = (s) % 18, tap_ = rem_ / 2, ch2_ = rem_ & 1;                     \
    int dy_ = tap_ / 3, dx_ = tap_ % 3;                                        \
    bf16x8 af[2][2];                                                           \
    _Pragma("unroll") for (int r = 0; r < 2; ++r) {                            \
      int rowk_ = ((dy_ + r) * 8 + ch2_ * 4 + kg) * 63;                        \
      _Pragma("unroll") for (int i = 0; i < 2; ++i)                            \
          af[r][i] = *(const bf16x8*)&Asm[rowk_ + wpx + i * 16 + q15 + dx_];   \
    }                                                                          \
    _Pragma("unroll") for (int r = 0; r < 2; ++r)                              \
        _Pragma("unroll") for (int i = 0; i < 2; ++i)                          \
            _Pragma("unroll") for (int j = 0; j < 4; ++j)                      \
                acc[r][i][j] = __builtin_amdgcn_mfma_f32_16x16x32_bf16(af[r][i], bp[j], acc[r][i][j], 0, 0, 0); \
  }

// triad: steps s, s+1, s+2 on bp0..bp2, prefetching s+3..s+5 (guarded)
#define TRIAD(s)                                                               \
  STEP(s, bp0); LOADBG(bp0, (s) + 3);                                          \
  STEP((s) + 1, bp1); LOADBG(bp1, (s) + 4);                                    \
  STEP((s) + 2, bp2); LOADBG(bp2, (s) + 5);

  bf16x8 bp0[4], bp1[4], bp2[4];
  STAGEA(0);
  LOADB(bp0, 0);
  LOADB(bp1, 1);
  LOADB(bp2, 2);
  __syncthreads();

  // T14: issue half-1 A loads now; latency hides under half-0 compute.
  int s0 = tid, s1 = tid + 512, s2 = tid + 1024, s3 = tid + 1536;
  int o0 = (s0 / 62) * 63 + s0 % 62;
  int o1 = (s1 / 62) * 63 + s1 % 62;
  int o2 = (s2 / 62) * 63 + s2 % 62;
  int o3 = (s3 / 62) * 63 + s3 % 62;
  bool a3ok = s3 < 1984;
  uint4 ar0 = A1SRC(s0);
  uint4 ar1 = A1SRC(s1);
  uint4 ar2 = A1SRC(s2);
  uint4 ar3 = a3ok ? A1SRC(s3) : make_uint4(0u, 0u, 0u, 0u);

  f32x4 acc[2][2][4] = {};

  TRIAD(0); TRIAD(3); TRIAD(6); TRIAD(9); TRIAD(12); TRIAD(15);
  __syncthreads();              // all reads of half-0 Asm complete
  Asm[o0] = ar0;
  Asm[o1] = ar1;
  Asm[o2] = ar2;
  if (a3ok) Asm[o3] = ar3;
  __syncthreads();
  TRIAD(18); TRIAD(21); TRIAD(24); TRIAD(27); TRIAD(30); TRIAD(33);
#undef TRIAD
#undef STEP
#undef LOADB
#undef LOADBG
#undef A1SRC
#undef STAGEA

  int ocbase = ocq * 64;
#pragma unroll
  for (int j = 0; j < 4; ++j) {
    int oc = ocbase + j * 16 + q15;
    float s = g[oc] * rsqrtf(var[oc] + 1e-5f);
    float mm = mu[oc], bb = be[oc];
#pragma unroll
    for (int r = 0; r < 2; ++r) {
#pragma unroll
      for (int i = 0; i < 2; ++i) {
        int pxb = wpx + i * 16 + kg * 4;
        if (pxb < 60) {
          float4 o4;
          o4.x = fmaxf((acc[r][i][j][0] - mm) * s + bb, 0.f);
          o4.y = fmaxf((acc[r][i][j][1] - mm) * s + bb, 0.f);
          o4.z = fmaxf((acc[r][i][j][2] - mm) * s + bb, 0.f);
          o4.w = fmaxf((acc[r][i][j][3] - mm) * s + bb, 0.f);
          *(float4*)(&out[(size_t)(b * 256 + oc) * HW + (h0 + r) * WIMG + w0 + pxb]) = o4;
        }
      }
    }
  }
}

// ---------------------------------------------------------------------------
extern "C" void kernel_launch(void* const* d_in, const int* in_sizes, int n_in,
                              void* d_out, int out_size, void* d_ws, size_t ws_size,
                              hipStream_t stream) {
  const float* camera = (const float*)d_in[0];
  const float* lidar  = (const float*)d_in[1];
  const float* cam_w  = (const float*)d_in[2];
  const float* cam_g  = (const float*)d_in[3];
  const float* cam_b  = (const float*)d_in[4];
  const float* cam_m  = (const float*)d_in[5];
  const float* cam_v  = (const float*)d_in[6];
  const float* lid_w  = (const float*)d_in[7];
  const float* lid_g  = (const float*)d_in[8];
  const float* lid_b  = (const float*)d_in[9];
  const float* lid_m  = (const float*)d_in[10];
  const float* lid_v  = (const float*)d_in[11];
  const float* ipw    = (const float*)d_in[12];
  const float* ipb    = (const float*)d_in[13];
  const float* opw    = (const float*)d_in[14];
  const float* opb    = (const float*)d_in[15];
  const float* ocw    = (const float*)d_in[16];
  const float* ocg    = (const float*)d_in[17];
  const float* ocb    = (const float*)d_in[18];
  const float* ocm    = (const float*)d_in[19];
  const float* ocv    = (const float*)d_in[20];

  __hip_bfloat16* ws = (__hip_bfloat16*)d_ws;
  const size_t NP = (size_t)2 * PSTRIDE * 128;
  __hip_bfloat16* cam_bf = ws;                    // aliased by fb later
  __hip_bfloat16* lid_bf = ws + NP;
  __hip_bfloat16* qc     = ws + 2 * NP;           // q, then ctx (in-place)
  __hip_bfloat16* kvb    = ws + 3 * NP;           // [p][256], 2*NP elements
  __hip_bfloat16* wipb   = ws + 5 * NP;           // 384*128
  __hip_bfloat16* wob    = wipb + 384 * 128;      // 128*128
  __hip_bfloat16* wcb    = wob + 128 * 128;       // 256*9*128 (frag-major)
  __hip_bfloat16* wcamb  = wcb + 256 * 9 * 128;   // 128*128 (Kpad=128)
  __hip_bfloat16* wlidb  = wcamb + 128 * 128;     // 128*256
  __hip_bfloat16* fbbuf  = cam_bf;

  dim3 blk(256);
  // fused weight prep (409600 items)
  hipLaunchKernelGGL(k_prep_all, dim3(1600), blk, 0, stream,
                     ipw, opw, ocw, cam_w, lid_w, wipb, wob, wcb, wcamb, wlidb);
  // projections -> pixel-major bf16 (MFMA implicit GEMM)
  dim3 gproj(254, 1, 2);
  hipLaunchKernelGGL(k_proj_mfma, gproj, blk, 0, stream,
                     camera, wcamb, cam_g, cam_b, cam_m, cam_v, cam_bf, 80, 128);
  hipLaunchKernelGGL(k_proj_mfma, gproj, blk, 0, stream,
                     lidar, wlidb, lid_g, lid_b, lid_m, lid_v, lid_bf, 256, 256);
  // qkv GEMMs (q scaled by log2(e)/4 for exp2-domain softmax)
  hipLaunchKernelGGL(k_gemm_bias, dim3(254, 1, 2), blk, 0, stream,
                     lid_bf, wipb, ipb, qc, 128, 128, QSCALE);
  hipLaunchKernelGGL(k_gemm_bias, dim3(254, 2, 2), blk, 0, stream,
                     cam_bf, wipb + 128 * 128, ipb + 128, kvb, 128, 256, 1.0f);
  // attention (qc -> qc in place) + absorbed fb border zeroing
  hipLaunchKernelGGL(k_attn_mfma, dim3(288, 8), blk, 0, stream, qc, kvb, qc, fbbuf);
  // out-proj + residual -> fb
  hipLaunchKernelGGL(k_outproj_mfma, dim3(254, 1, 2), blk, 0, stream,
                     qc, wob, opb, lid_bf, fbbuf);
  // conv + BN + ReLU  (2 rows x 60 px x 256 oc, async half-1 staging)
  hipLaunchKernelGGL(k_conv_mfma, dim3(270, 1, 2), dim3(512), 0, stream,
                     fbbuf, wcb, ocg, ocb, ocm, ocv, (float*)d_out);
}

// Round 21
// 270.794 us; speedup vs baseline: 1.4928x; 1.4928x over previous
//
#include <hip/hip_runtime.h>
#include <hip/hip_bf16.h>
#include <cmath>

#define HW      32400
#define WIMG    180
#define DD      128
#define NHEADS  8
#define DHEAD   16
#define LTOK    225
#define PSTRIDE 64928            // 32400 + slack per batch
#define FBROW   188
#define FBH     182
#define FBSZ    ((size_t)FBH * FBROW * 128)   // padded pixel-major conv input per batch
#define QSCALE  0.36067376022224085f          // log2(e)/4, folded into q projection

typedef __attribute__((ext_vector_type(8))) short bf16x8;
typedef __attribute__((ext_vector_type(4))) short bf16x4;
typedef __attribute__((ext_vector_type(4))) float f32x4;

union U16B { uint4 u; int4 i; bf16x8 v; };
union U8B  { uint2 u; bf16x4 v; };

__device__ __forceinline__ bf16x8 ldfrag(const __hip_bfloat16* p, int ld, int lane) {
  // fragment for mfma_f32_16x16x32_bf16: row = lane&15 (stride ld), k = (lane>>4)*8..+7 contiguous
  return *(const bf16x8*)(p + (size_t)(lane & 15) * ld + ((lane >> 4) << 3));
}

__device__ __forceinline__ float bf2f(unsigned int u) {
  return __uint_as_float(u << 16);
}

__device__ __forceinline__ unsigned short f2bf(float x) {
  unsigned int b = __float_as_uint(x);
  return (unsigned short)((b + 0x7fffu + ((b >> 16) & 1u)) >> 16);
}

// ---------------------------------------------------------------------------
// weight prep (all 5 preps fused into one launch)
// ---------------------------------------------------------------------------
__global__ void k_prep_all(
    const float* __restrict__ ipw, const float* __restrict__ opw,
    const float* __restrict__ ocw, const float* __restrict__ cam_w,
    const float* __restrict__ lid_w,
    __hip_bfloat16* __restrict__ wipb, __hip_bfloat16* __restrict__ wob,
    __hip_bfloat16* __restrict__ wcb, __hip_bfloat16* __restrict__ wcamb,
    __hip_bfloat16* __restrict__ wlidb) {
  int i = blockIdx.x * 256 + threadIdx.x;
  if (i < 49152) { wipb[i] = __float2bfloat16(ipw[i]); return; }
  i -= 49152;
  if (i < 16384) { wob[i] = __float2bfloat16(opw[i]); return; }
  i -= 16384;
  if (i < 294912) {
    // conv weights -> frag-major: [oc16(16)][tap(9)][chunk(4)][lane(64)][e(8)]
    int oc16  = i / 18432;
    int r0    = i % 18432;
    int tap   = r0 / 2048;
    int r1    = r0 % 2048;
    int chunk = r1 / 512;
    int r2    = r1 % 512;
    int lane  = r2 / 8;
    int e     = r2 % 8;
    int oc = oc16 * 16 + (lane & 15);
    int ic = chunk * 32 + (lane >> 4) * 8 + e;
    wcb[i] = __float2bfloat16(ocw[(size_t)(oc * 128 + ic) * 9 + tap]);
    return;
  }
  i -= 294912;
  if (i < 16384) {           // cam proj weights, C=80 zero-padded to Kpad=128
    int d = i / 128, c = i % 128;
    wcamb[i] = (c < 80) ? __float2bfloat16(cam_w[d * 80 + c]) : __float2bfloat16(0.f);
    return;
  }
  i -= 16384;
  if (i < 32768) { wlidb[i] = __float2bfloat16(lid_w[i]); return; }  // C==Kpad==256
}

// ---------------------------------------------------------------------------
// 1) 1x1 conv + BN + ReLU as implicit MFMA GEMM — cam & lid merged in one
//    launch (blockIdx.y selects input); both halves fully parallel.
// ---------------------------------------------------------------------------
__global__ void __launch_bounds__(256) k_proj_mfma(
    const float* __restrict__ camera, const float* __restrict__ lidar,
    const __hip_bfloat16* __restrict__ wcamb, const __hip_bfloat16* __restrict__ wlidb,
    const float* __restrict__ cam_g, const float* __restrict__ cam_b,
    const float* __restrict__ cam_m, const float* __restrict__ cam_v,
    const float* __restrict__ lid_g, const float* __restrict__ lid_b,
    const float* __restrict__ lid_m, const float* __restrict__ lid_v,
    __hip_bfloat16* __restrict__ cam_bf, __hip_bfloat16* __restrict__ lid_bf) {
  const float* in; const __hip_bfloat16* wb;
  const float *g, *be, *mu, *var;
  __hip_bfloat16* outp;
  int C, Kpad;
  if (blockIdx.y == 0) {
    in = camera; wb = wcamb; g = cam_g; be = cam_b; mu = cam_m; var = cam_v;
    outp = cam_bf; C = 80; Kpad = 128;
  } else {
    in = lidar; wb = wlidb; g = lid_g; be = lid_b; mu = lid_m; var = lid_v;
    outp = lid_bf; C = 256; Kpad = 256;
  }
  __shared__ __align__(16) __hip_bfloat16 sa[128 * 64];
  int m0 = blockIdx.x * 128;
  int b = blockIdx.z;
  int tid = threadIdx.x, lane = tid & 63, wid = tid >> 6;
  int wm = (wid >> 1) * 64, wn = (wid & 1) * 64;
  const float* inb = in + (size_t)b * C * HW;
  int sp = (tid >> 1) & 127;
  int sc4 = (tid & 1) * 4;
  int gp = m0 + sp;
  bool pok = gp < HW;
  f32x4 acc[4][4] = {};
  for (int kc = 0; kc < Kpad; kc += 64) {
    __syncthreads();
#pragma unroll
    for (int it = 0; it < 8; ++it) {
      int lc = sc4 + it * 8;
      int c = kc + lc;
      unsigned short u[4];
#pragma unroll
      for (int j = 0; j < 4; ++j) {
        float x = (pok && (c + j) < C) ? inb[(size_t)(c + j) * HW + gp] : 0.f;
        u[j] = f2bf(x);
      }
      int blk = (lc >> 3) ^ (sp & 7);
      char* dst = (char*)sa + sp * 128 + blk * 16 + (lc & 7) * 2;
      *(uint2*)dst = make_uint2(((unsigned)u[1] << 16) | u[0],
                                ((unsigned)u[3] << 16) | u[2]);
    }
    __syncthreads();
#pragma unroll
    for (int ks = 0; ks < 2; ++ks) {
      bf16x8 af[4], bfr[4];
#pragma unroll
      for (int i = 0; i < 4; ++i) {
        int pr = wm + i * 16 + (lane & 15);
        int blk = ((ks * 4 + (lane >> 4)) ^ (pr & 7));
        af[i] = *(const bf16x8*)((const char*)sa + pr * 128 + blk * 16);
      }
#pragma unroll
      for (int j = 0; j < 4; ++j)
        bfr[j] = ldfrag(wb + (size_t)(wn + j * 16) * Kpad + kc + ks * 32, Kpad, lane);
#pragma unroll
      for (int i = 0; i < 4; ++i)
#pragma unroll
        for (int j = 0; j < 4; ++j)
          acc[i][j] = __builtin_amdgcn_mfma_f32_16x16x32_bf16(af[i], bfr[j], acc[i][j], 0, 0, 0);
    }
  }
  int col = lane & 15, rq = lane >> 4;
  __hip_bfloat16* ob = outp + (size_t)b * PSTRIDE * 128;
#pragma unroll
  for (int j = 0; j < 4; ++j) {
    int d = wn + j * 16 + col;
    float s = g[d] * rsqrtf(var[d] + 1e-5f);
    float mm = mu[d], bb = be[d];
#pragma unroll
    for (int i = 0; i < 4; ++i) {
#pragma unroll
      for (int r = 0; r < 4; ++r) {
        int m = m0 + wm + i * 16 + rq * 4 + r;
        if (m < HW) {
          float y = (acc[i][j][r] - mm) * s + bb;
          ob[(size_t)m * 128 + d] = __float2bfloat16(fmaxf(y, 0.f));
        }
      }
    }
  }
}

// ---------------------------------------------------------------------------
// 2) q + kv GEMMs merged in one launch: y=0 -> q (from lid), y=1,2 -> kv
//    (from cam, N-block y-1). All K=128.
// ---------------------------------------------------------------------------
__global__ void __launch_bounds__(256) k_qkv_gemm(
    const __hip_bfloat16* __restrict__ lid_bf, const __hip_bfloat16* __restrict__ cam_bf,
    const __hip_bfloat16* __restrict__ wipb, const float* __restrict__ ipb,
    __hip_bfloat16* __restrict__ qc, __hip_bfloat16* __restrict__ kvb) {
  int yy = blockIdx.y;
  const __hip_bfloat16* A;
  const __hip_bfloat16* B;
  const float* bias;
  __hip_bfloat16* out;
  int ldout, n0;
  float oscale;
  if (yy == 0) {
    A = lid_bf; B = wipb; bias = ipb; out = qc; ldout = 128; n0 = 0; oscale = QSCALE;
  } else {
    A = cam_bf; B = wipb + 128 * 128; bias = ipb + 128; out = kvb;
    ldout = 256; n0 = (yy - 1) * 128; oscale = 1.0f;
  }
  int m0 = blockIdx.x * 128, b = blockIdx.z;
  int lane = threadIdx.x & 63, wid = threadIdx.x >> 6;
  int wm = (wid >> 1) * 64, wn = (wid & 1) * 64;
  const __hip_bfloat16* Ab = A + (size_t)b * PSTRIDE * 128;
  f32x4 acc[4][4] = {};
  for (int kc = 0; kc < 128; kc += 32) {
    bf16x8 af[4], bfr[4];
#pragma unroll
    for (int i = 0; i < 4; ++i)
      af[i] = ldfrag(Ab + (size_t)(m0 + wm + i * 16) * 128 + kc, 128, lane);
#pragma unroll
    for (int j = 0; j < 4; ++j)
      bfr[j] = ldfrag(B + (size_t)(n0 + wn + j * 16) * 128 + kc, 128, lane);
#pragma unroll
    for (int i = 0; i < 4; ++i)
#pragma unroll
      for (int j = 0; j < 4; ++j)
        acc[i][j] = __builtin_amdgcn_mfma_f32_16x16x32_bf16(af[i], bfr[j], acc[i][j], 0, 0, 0);
  }
  int col = lane & 15, rq = lane >> 4;
  __hip_bfloat16* ob = out + (size_t)b * PSTRIDE * ldout;
#pragma unroll
  for (int j = 0; j < 4; ++j) {
    int n = n0 + wn + j * 16 + col;
    float bs = bias[n];
#pragma unroll
    for (int i = 0; i < 4; ++i) {
#pragma unroll
      for (int r = 0; r < 4; ++r) {
        int m = m0 + wm + i * 16 + rq * 4 + r;
        if (m < HW) ob[(size_t)m * ldout + n] = __float2bfloat16((acc[i][j][r] + bs) * oscale);
      }
    }
  }
}

// ---------------------------------------------------------------------------
// 3) MFMA flash attention per (bn, head) — 16x16x16 MFMA, P stays in regs.
//    Also absorbs the fb-border zeroing (fbbuf disjoint from qc/kvb).
// ---------------------------------------------------------------------------
__global__ void __launch_bounds__(256) k_attn_mfma(
    const __hip_bfloat16* __restrict__ qc, const __hip_bfloat16* __restrict__ kvb,
    __hip_bfloat16* __restrict__ ctx, __hip_bfloat16* __restrict__ fbb) {
  __shared__ __align__(8) uint2 Kf[15 * 64];   // frag-major K: lane(g,q)=K[key q][d g*4..+3]
  __shared__ __align__(8) uint2 Vf[15 * 64];   // frag-major V^T: lane(g,q)=V^T[d q][key g*4..+3]
  int bn = blockIdx.x, hh = blockIdx.y;
  int b = bn / 144, rr = bn % 144, tby = rr / 12, tbx = rr % 12;
  int tid = threadIdx.x;
  int pbase = tby * 15 * WIMG + tbx * 15;
  const __hip_bfloat16* kvbase = kvb + (size_t)b * PSTRIDE * 256 + hh * 16;

  // ---- absorbed fb border zeroing (92*256 = 23552 items exactly) ----
  if (hh == 0 && bn < 92) {
    int idx = bn * 256 + tid;
    int zb = idx / (736 * 16);
    int r = idx % (736 * 16);
    int px = r >> 4, blk = r & 15;
    int row, col;
    if (px < 188)      { row = 0;            col = px; }
    else if (px < 376) { row = 181;          col = px - 188; }
    else if (px < 556) { row = px - 376 + 1; col = 0; }
    else               { row = px - 556 + 1; col = 181; }
    ((uint4*)(fbb + (size_t)zb * FBSZ + ((size_t)row * FBROW + col) * 128))[blk] =
        make_uint4(0u, 0u, 0u, 0u);
  }

  // ---- stage K and V^T into frag-major layout ----
  if (tid < 240) {
    int row = tid;
    int ck = row >> 4, q = row & 15;
    uint4 k0 = make_uint4(0, 0, 0, 0), k1 = k0, v0 = k0, v1 = k0;
    if (row < LTOK) {
      int p = pbase + (row / 15) * WIMG + (row % 15);
      const uint4* kp = (const uint4*)(kvbase + (size_t)p * 256);
      k0 = kp[0]; k1 = kp[1];
      v0 = kp[16]; v1 = kp[17];     // V at +128 elements
    }
    Kf[ck * 64 + q]      = make_uint2(k0.x, k0.y);
    Kf[ck * 64 + 16 + q] = make_uint2(k0.z, k0.w);
    Kf[ck * 64 + 32 + q] = make_uint2(k1.x, k1.y);
    Kf[ck * 64 + 48 + q] = make_uint2(k1.z, k1.w);
    unsigned short vv[16];
    *(uint4*)&vv[0] = v0;
    *(uint4*)&vv[8] = v1;
    int vg = q >> 2, vj = q & 3;
    unsigned short* vb = (unsigned short*)&Vf[ck * 64 + vg * 16];
#pragma unroll
    for (int d0 = 0; d0 < 16; ++d0) {
      int d = (d0 + q) & 15;
      vb[d * 4 + vj] = vv[d];
    }
  }
  __syncthreads();

  int lane = tid & 63, wid = tid >> 6;
  int g = lane >> 4, q15 = lane & 15;
  int wq0 = wid * 64;
  const uint2* KfB = Kf + lane;
  const uint2* VfB = Vf + lane;

  // Q fragments: lane(g,q15) = Q[query q15][d g*4..+3] — full dh, no padding
  bf16x4 qf[4];
#pragma unroll
  for (int i = 0; i < 4; ++i) {
    int q = wq0 + i * 16 + q15;
    int qq = q < LTOK ? q : 0;
    int p = pbase + (qq / 15) * WIMG + (qq % 15);
    U8B u;
    u.u = *(const uint2*)(qc + ((size_t)b * PSTRIDE + p) * 128 + hh * 16 + g * 4);
    qf[i] = u.v;
  }

  float ls[4] = {0.f, 0.f, 0.f, 0.f};
  f32x4 oac[4] = {};
#pragma unroll 1
  for (int ck = 0; ck < 15; ++ck) {
    U8B ku; ku.u = KfB[ck * 64];
    U8B vu; vu.u = VfB[ck * 64];
    bf16x4 kf = ku.v, vf = vu.v;
#pragma unroll
    for (int i = 0; i < 4; ++i) {
      f32x4 st = {0.f, 0.f, 0.f, 0.f};
      asm("v_mfma_f32_16x16x16_bf16 %0, %1, %2, %0" : "+v"(st) : "v"(kf), "v"(qf[i]));
      float p0 = exp2f(st[0]);
      float p1 = exp2f(st[1]);
      float p2 = exp2f(st[2]);
      float p3 = exp2f(st[3]);
      if (ck == 14) {                  // keys 224..239: only key 224 (g=0,r=0) valid
        if (g) p0 = 0.f;
        p1 = 0.f; p2 = 0.f; p3 = 0.f;
      }
      ls[i] += (p0 + p1) + (p2 + p3);
      U8B pu;
      pu.u = make_uint2((unsigned)f2bf(p0) | ((unsigned)f2bf(p1) << 16),
                        (unsigned)f2bf(p2) | ((unsigned)f2bf(p3) << 16));
      asm("v_mfma_f32_16x16x16_bf16 %0, %1, %2, %0" : "+v"(oac[i]) : "v"(vf), "v"(pu.v));
    }
  }
#pragma unroll
  for (int i = 0; i < 4; ++i) {
    ls[i] += __shfl_xor(ls[i], 16);
    ls[i] += __shfl_xor(ls[i], 32);
  }

  // ---- epilogue: normalize and store (lane owns ctx[q][hh*16 + g*4 .. +3]) ----
  __hip_bfloat16* cb = ctx + (size_t)b * PSTRIDE * 128 + hh * 16;
#pragma unroll
  for (int i = 0; i < 4; ++i) {
    float inv = 1.f / ls[i];
    int qo = wq0 + i * 16 + q15;
    if (qo < LTOK) {
      unsigned lo = (unsigned)f2bf(oac[i][0] * inv) | ((unsigned)f2bf(oac[i][1] * inv) << 16);
      unsigned hi = (unsigned)f2bf(oac[i][2] * inv) | ((unsigned)f2bf(oac[i][3] * inv) << 16);
      int p = pbase + (qo / 15) * WIMG + (qo % 15);
      *(uint2*)(cb + (size_t)p * 128 + g * 4) = make_uint2(lo, hi);
    }
  }
}

// ---------------------------------------------------------------------------
// 4) out-proj MFMA GEMM + bias + residual -> padded fb bf16
// ---------------------------------------------------------------------------
__global__ void __launch_bounds__(256) k_outproj_mfma(
    const __hip_bfloat16* __restrict__ ctx, const __hip_bfloat16* __restrict__ wob,
    const float* __restrict__ opb, const __hip_bfloat16* __restrict__ lidb,
    __hip_bfloat16* __restrict__ fb) {
  int m0 = blockIdx.x * 128, b = blockIdx.z;
  int lane = threadIdx.x & 63, wid = threadIdx.x >> 6;
  int wm = (wid >> 1) * 64, wn = (wid & 1) * 64;
  const __hip_bfloat16* Ab = ctx + (size_t)b * PSTRIDE * 128;
  f32x4 acc[4][4] = {};
  for (int kc = 0; kc < 128; kc += 32) {
    bf16x8 af[4], bfr[4];
#pragma unroll
    for (int i = 0; i < 4; ++i)
      af[i] = ldfrag(Ab + (size_t)(m0 + wm + i * 16) * 128 + kc, 128, lane);
#pragma unroll
    for (int j = 0; j < 4; ++j)
      bfr[j] = ldfrag(wob + (size_t)(wn + j * 16) * 128 + kc, 128, lane);
#pragma unroll
    for (int i = 0; i < 4; ++i)
#pragma unroll
      for (int j = 0; j < 4; ++j)
        acc[i][j] = __builtin_amdgcn_mfma_f32_16x16x32_bf16(af[i], bfr[j], acc[i][j], 0, 0, 0);
  }
  int col = lane & 15, rq = lane >> 4;
  const __hip_bfloat16* lb = lidb + (size_t)b * PSTRIDE * 128;
  __hip_bfloat16* fbp = fb + (size_t)b * FBSZ;
#pragma unroll
  for (int j = 0; j < 4; ++j) {
    int n = wn + j * 16 + col;
    float bs = opb[n];
#pragma unroll
    for (int i = 0; i < 4; ++i) {
#pragma unroll
      for (int r = 0; r < 4; ++r) {
        int m = m0 + wm + i * 16 + rq * 4 + r;
        if (m < HW) {
          float v = acc[i][j][r] + bs + __bfloat162float(lb[(size_t)m * 128 + n]);
          int hhh = m / WIMG, www = m % WIMG;
          fbp[((size_t)(hhh + 1) * FBROW + (www + 1)) * 128 + n] = __float2bfloat16(v);
        }
      }
    }
  }
}

// ---------------------------------------------------------------------------
// 5) 3x3 conv 128->256 + BN + ReLU: 2 rows x 60 px x 256 oc per block,
//    ic-halved LDS A staging (row stride 63), 3-deep B register prefetch.
//    NO min-waves bound (r14/r20 lesson: (512,4) caps VGPR at 64 -> spill).
// ---------------------------------------------------------------------------
__global__ void __launch_bounds__(512) k_conv_mfma(
    const __hip_bfloat16* __restrict__ fb, const __hip_bfloat16* __restrict__ wcb,
    const float* __restrict__ g, const float* __restrict__ be,
    const float* __restrict__ mu, const float* __restrict__ var,
    float* __restrict__ out) {
  __shared__ __align__(16) uint4 Asm[32 * 63];   // [dy(4)*8+kgrp8][px], row stride 63
  int bx = blockIdx.x;                 // 0..269: hpair*3 + strip
  int hp = bx / 3, strip = bx % 3;
  int h0 = hp * 2;                     // output rows h0, h0+1
  int w0 = strip * 60;
  int b = blockIdx.z;
  int tid = threadIdx.x, lane = tid & 63, wid = tid >> 6;   // wid 0..7
  int q15 = lane & 15, kg = lane >> 4;
  int wpx = (wid & 1) * 32;            // pixel half
  int ocq = wid >> 1;                  // oc quarter (0..3)
  const __hip_bfloat16* fbb = fb + (size_t)b * FBSZ;
  const __hip_bfloat16* Bw = wcb + (size_t)(ocq * 4) * 18432 + lane * 8;

#define STAGEA(half)                                                           \
  {                                                                            \
    _Pragma("unroll") for (int it = 0; it < 4; ++it) {                         \
      int slot = it * 512 + tid;                                               \
      if (slot < 1984) {                                                       \
        int px = slot % 62;                                                    \
        int rowk = slot / 62;          /* dy*8 + k8 */                         \
        int dy = rowk >> 3, k8 = rowk & 7;                                     \
        Asm[rowk * 63 + px] = *(const uint4*)(fbb + ((size_t)(h0 + dy) * FBROW + (w0 + px)) * 128 + ((half) * 8 + k8) * 8); \
      }                                                                        \
    }                                                                          \
  }

// global step s (0..35): half = s/18, tap = (s%18)/2, ch2 = s&1
#define LOADB(dst, s)                                                          \
  {                                                                            \
    int half_ = (s) / 18, rem_ = (s) % 18, tap_ = rem_ / 2, ch2_ = rem_ & 1;   \
    int chunk_ = half_ * 2 + ch2_;                                             \
    _Pragma("unroll") for (int j = 0; j < 4; ++j)                              \
        dst[j] = *(const bf16x8*)(Bw + (size_t)j * 18432 + tap_ * 2048 + chunk_ * 512); \
  }

#define LOADBG(dst, s)                                                         \
  { if ((s) < 36) LOADB(dst, s); }

#define STEP(s, bp)                                                            \
  {                                                                            \
    int rem_ = (s) % 18, tap_ = rem_ / 2, ch2_ = rem_ & 1;                     \
    int dy_ = tap_ / 3, dx_ = tap_ % 3;                                        \
    bf16x8 af[2][2];                                                           \
    _Pragma("unroll") for (int r = 0; r < 2; ++r) {                            \
      int rowk_ = ((dy_ + r) * 8 + ch2_ * 4 + kg) * 63;                        \
      _Pragma("unroll") for (int i = 0; i < 2; ++i)                            \
          af[r][i] = *(const bf16x8*)&Asm[rowk_ + wpx + i * 16 + q15 + dx_];   \
    }                                                                          \
    _Pragma("unroll") for (int r = 0; r < 2; ++r)                              \
        _Pragma("unroll") for (int i = 0; i < 2; ++i)                          \
            _Pragma("unroll") for (int j = 0; j < 4; ++j)                      \
                acc[r][i][j] = __builtin_amdgcn_mfma_f32_16x16x32_bf16(af[r][i], bp[j], acc[r][i][j], 0, 0, 0); \
  }

// triad: steps s, s+1, s+2 on bp0..bp2, prefetching s+3..s+5 (guarded)
#define TRIAD(s)                                                               \
  STEP(s, bp0); LOADBG(bp0, (s) + 3);                                          \
  STEP((s) + 1, bp1); LOADBG(bp1, (s) + 4);                                    \
  STEP((s) + 2, bp2); LOADBG(bp2, (s) + 5);

  bf16x8 bp0[4], bp1[4], bp2[4];
  STAGEA(0);
  LOADB(bp0, 0);
  LOADB(bp1, 1);
  LOADB(bp2, 2);
  __syncthreads();

  f32x4 acc[2][2][4] = {};

  TRIAD(0); TRIAD(3); TRIAD(6); TRIAD(9); TRIAD(12); TRIAD(15);
  __syncthreads();              // all reads of half-0 Asm complete
  STAGEA(1);
  __syncthreads();
  TRIAD(18); TRIAD(21); TRIAD(24); TRIAD(27); TRIAD(30); TRIAD(33);
#undef TRIAD
#undef STEP
#undef LOADB
#undef LOADBG
#undef STAGEA

  int ocbase = ocq * 64;
#pragma unroll
  for (int j = 0; j < 4; ++j) {
    int oc = ocbase + j * 16 + q15;
    float s = g[oc] * rsqrtf(var[oc] + 1e-5f);
    float mm = mu[oc], bb = be[oc];
#pragma unroll
    for (int r = 0; r < 2; ++r) {
#pragma unroll
      for (int i = 0; i < 2; ++i) {
        int pxb = wpx + i * 16 + kg * 4;
        if (pxb < 60) {
          float4 o4;
          o4.x = fmaxf((acc[r][i][j][0] - mm) * s + bb, 0.f);
          o4.y = fmaxf((acc[r][i][j][1] - mm) * s + bb, 0.f);
          o4.z = fmaxf((acc[r][i][j][2] - mm) * s + bb, 0.f);
          o4.w = fmaxf((acc[r][i][j][3] - mm) * s + bb, 0.f);
          *(float4*)(&out[(size_t)(b * 256 + oc) * HW + (h0 + r) * WIMG + w0 + pxb]) = o4;
        }
      }
    }
  }
}

// ---------------------------------------------------------------------------
extern "C" void kernel_launch(void* const* d_in, const int* in_sizes, int n_in,
                              void* d_out, int out_size, void* d_ws, size_t ws_size,
                              hipStream_t stream) {
  const float* camera = (const float*)d_in[0];
  const float* lidar  = (const float*)d_in[1];
  const float* cam_w  = (const float*)d_in[2];
  const float* cam_g  = (const float*)d_in[3];
  const float* cam_b  = (const float*)d_in[4];
  const float* cam_m  = (const float*)d_in[5];
  const float* cam_v  = (const float*)d_in[6];
  const float* lid_w  = (const float*)d_in[7];
  const float* lid_g  = (const float*)d_in[8];
  const float* lid_b  = (const float*)d_in[9];
  const float* lid_m  = (const float*)d_in[10];
  const float* lid_v  = (const float*)d_in[11];
  const float* ipw    = (const float*)d_in[12];
  const float* ipb    = (const float*)d_in[13];
  const float* opw    = (const float*)d_in[14];
  const float* opb    = (const float*)d_in[15];
  const float* ocw    = (const float*)d_in[16];
  const float* ocg    = (const float*)d_in[17];
  const float* ocb    = (const float*)d_in[18];
  const float* ocm    = (const float*)d_in[19];
  const float* ocv    = (const float*)d_in[20];

  __hip_bfloat16* ws = (__hip_bfloat16*)d_ws;
  const size_t NP = (size_t)2 * PSTRIDE * 128;
  __hip_bfloat16* cam_bf = ws;                    // aliased by fb later
  __hip_bfloat16* lid_bf = ws + NP;
  __hip_bfloat16* qc     = ws + 2 * NP;           // q, then ctx (in-place)
  __hip_bfloat16* kvb    = ws + 3 * NP;           // [p][256], 2*NP elements
  __hip_bfloat16* wipb   = ws + 5 * NP;           // 384*128
  __hip_bfloat16* wob    = wipb + 384 * 128;      // 128*128
  __hip_bfloat16* wcb    = wob + 128 * 128;       // 256*9*128 (frag-major)
  __hip_bfloat16* wcamb  = wcb + 256 * 9 * 128;   // 128*128 (Kpad=128)
  __hip_bfloat16* wlidb  = wcamb + 128 * 128;     // 128*256
  __hip_bfloat16* fbbuf  = cam_bf;

  dim3 blk(256);
  // fused weight prep (409600 items)
  hipLaunchKernelGGL(k_prep_all, dim3(1600), blk, 0, stream,
                     ipw, opw, ocw, cam_w, lid_w, wipb, wob, wcb, wcamb, wlidb);
  // projections (cam + lid merged, fully parallel) -> pixel-major bf16
  hipLaunchKernelGGL(k_proj_mfma, dim3(254, 2, 2), blk, 0, stream,
                     camera, lidar, wcamb, wlidb,
                     cam_g, cam_b, cam_m, cam_v,
                     lid_g, lid_b, lid_m, lid_v,
                     cam_bf, lid_bf);
  // q + kv GEMMs merged (q scaled by log2(e)/4 for exp2-domain softmax)
  hipLaunchKernelGGL(k_qkv_gemm, dim3(254, 3, 2), blk, 0, stream,
                     lid_bf, cam_bf, wipb, ipb, qc, kvb);
  // attention (qc -> qc in place) + absorbed fb border zeroing
  hipLaunchKernelGGL(k_attn_mfma, dim3(288, 8), blk, 0, stream, qc, kvb, qc, fbbuf);
  // out-proj + residual -> fb
  hipLaunchKernelGGL(k_outproj_mfma, dim3(254, 1, 2), blk, 0, stream,
                     qc, wob, opb, lid_bf, fbbuf);
  // conv + BN + ReLU  (2 rows x 60 px x 256 oc, ic-halved LDS, 3-deep B)
  hipLaunchKernelGGL(k_conv_mfma, dim3(270, 1, 2), dim3(512), 0, stream,
                     fbbuf, wcb, ocg, ocb, ocm, ocv, (float*)d_out);
}

// Round 22
// 259.327 us; speedup vs baseline: 1.5588x; 1.0442x over previous
//
#include <hip/hip_runtime.h>
#include <hip/hip_bf16.h>
#include <cmath>

#define HW      32400
#define WIMG    180
#define DD      128
#define NHEADS  8
#define DHEAD   16
#define LTOK    225
#define PSTRIDE 64928            // 32400 + slack per batch
#define FBROW   188
#define FBH     182
#define FBSZ    ((size_t)FBH * FBROW * 128)   // padded pixel-major conv input per batch
#define QSCALE  0.36067376022224085f          // log2(e)/4, folded into q projection

typedef __attribute__((ext_vector_type(8))) short bf16x8;
typedef __attribute__((ext_vector_type(4))) short bf16x4;
typedef __attribute__((ext_vector_type(4))) float f32x4;

union U16B { uint4 u; int4 i; bf16x8 v; };
union U8B  { uint2 u; bf16x4 v; };

__device__ __forceinline__ bf16x8 ldfrag(const __hip_bfloat16* p, int ld, int lane) {
  // fragment for mfma_f32_16x16x32_bf16: row = lane&15 (stride ld), k = (lane>>4)*8..+7 contiguous
  return *(const bf16x8*)(p + (size_t)(lane & 15) * ld + ((lane >> 4) << 3));
}

__device__ __forceinline__ float bf2f(unsigned int u) {
  return __uint_as_float(u << 16);
}

__device__ __forceinline__ unsigned short f2bf(float x) {
  unsigned int b = __float_as_uint(x);
  return (unsigned short)((b + 0x7fffu + ((b >> 16) & 1u)) >> 16);
}

// ---------------------------------------------------------------------------
// weight prep (all 5 preps fused into one launch)
// ---------------------------------------------------------------------------
__global__ void k_prep_all(
    const float* __restrict__ ipw, const float* __restrict__ opw,
    const float* __restrict__ ocw, const float* __restrict__ cam_w,
    const float* __restrict__ lid_w,
    __hip_bfloat16* __restrict__ wipb, __hip_bfloat16* __restrict__ wob,
    __hip_bfloat16* __restrict__ wcb, __hip_bfloat16* __restrict__ wcamb,
    __hip_bfloat16* __restrict__ wlidb) {
  int i = blockIdx.x * 256 + threadIdx.x;
  if (i < 49152) { wipb[i] = __float2bfloat16(ipw[i]); return; }
  i -= 49152;
  if (i < 16384) { wob[i] = __float2bfloat16(opw[i]); return; }
  i -= 16384;
  if (i < 294912) {
    // conv weights -> frag-major: [oc16(16)][tap(9)][chunk(4)][lane(64)][e(8)]
    int oc16  = i / 18432;
    int r0    = i % 18432;
    int tap   = r0 / 2048;
    int r1    = r0 % 2048;
    int chunk = r1 / 512;
    int r2    = r1 % 512;
    int lane  = r2 / 8;
    int e     = r2 % 8;
    int oc = oc16 * 16 + (lane & 15);
    int ic = chunk * 32 + (lane >> 4) * 8 + e;
    wcb[i] = __float2bfloat16(ocw[(size_t)(oc * 128 + ic) * 9 + tap]);
    return;
  }
  i -= 294912;
  if (i < 16384) {           // cam proj weights, C=80 zero-padded to Kpad=128
    int d = i / 128, c = i % 128;
    wcamb[i] = (c < 80) ? __float2bfloat16(cam_w[d * 80 + c]) : __float2bfloat16(0.f);
    return;
  }
  i -= 16384;
  if (i < 32768) { wlidb[i] = __float2bfloat16(lid_w[i]); return; }  // C==Kpad==256
}

// ---------------------------------------------------------------------------
// 1) 1x1 conv + BN + ReLU as implicit MFMA GEMM — cam & lid merged; staging
//    uses float4 loads (8ch x 32px per wave-instr, 1KB) + T14 issue-early
//    prefetch of the next kc-step; one ds_write_b128 per pixel, full bank
//    spread via blk = c8g ^ (px&7) (frag-read layout unchanged).
// ---------------------------------------------------------------------------
__global__ void __launch_bounds__(256) k_proj_mfma(
    const float* __restrict__ camera, const float* __restrict__ lidar,
    const __hip_bfloat16* __restrict__ wcamb, const __hip_bfloat16* __restrict__ wlidb,
    const float* __restrict__ cam_g, const float* __restrict__ cam_b,
    const float* __restrict__ cam_m, const float* __restrict__ cam_v,
    const float* __restrict__ lid_g, const float* __restrict__ lid_b,
    const float* __restrict__ lid_m, const float* __restrict__ lid_v,
    __hip_bfloat16* __restrict__ cam_bf, __hip_bfloat16* __restrict__ lid_bf) {
  const float* in; const __hip_bfloat16* wb;
  const float *g, *be, *mu, *var;
  __hip_bfloat16* outp;
  int C, Kpad;
  if (blockIdx.y == 0) {
    in = camera; wb = wcamb; g = cam_g; be = cam_b; mu = cam_m; var = cam_v;
    outp = cam_bf; C = 80; Kpad = 128;
  } else {
    in = lidar; wb = wlidb; g = lid_g; be = lid_b; mu = lid_m; var = lid_v;
    outp = lid_bf; C = 256; Kpad = 256;
  }
  __shared__ __align__(16) __hip_bfloat16 sa[128 * 64];
  int m0 = blockIdx.x * 128;
  int b = blockIdx.z;
  int tid = threadIdx.x, lane = tid & 63, wid = tid >> 6;
  int wm = (wid >> 1) * 64, wn = (wid & 1) * 64;
  const float* inb = in + (size_t)b * C * HW;

  // staging mapping: c8g = 8-channel group, pq = pixel quad (4 px)
  int c8g = tid & 7;
  int pq  = tid >> 3;          // 0..31
  int px0 = pq * 4;
  int gp0 = m0 + px0;
  bool pok = gp0 < HW;         // quad fully in-bounds (HW and px0 multiples of 4)

  float4 xv[8];
#define LOADP(kcv)                                                             \
  {                                                                            \
    _Pragma("unroll") for (int j = 0; j < 8; ++j) {                            \
      int c = (kcv) + c8g * 8 + j;                                             \
      xv[j] = (pok && c < C) ? *(const float4*)(inb + (size_t)c * HW + gp0)    \
                             : make_float4(0.f, 0.f, 0.f, 0.f);                \
    }                                                                          \
  }

  LOADP(0);
  f32x4 acc[4][4] = {};
  for (int kc = 0; kc < Kpad; kc += 64) {
    __syncthreads();           // prior iteration's LDS frag reads complete
#pragma unroll
    for (int pi = 0; pi < 4; ++pi) {
      float e0 = (pi == 0) ? xv[0].x : (pi == 1) ? xv[0].y : (pi == 2) ? xv[0].z : xv[0].w;
      float e1 = (pi == 0) ? xv[1].x : (pi == 1) ? xv[1].y : (pi == 2) ? xv[1].z : xv[1].w;
      float e2 = (pi == 0) ? xv[2].x : (pi == 1) ? xv[2].y : (pi == 2) ? xv[2].z : xv[2].w;
      float e3 = (pi == 0) ? xv[3].x : (pi == 1) ? xv[3].y : (pi == 2) ? xv[3].z : xv[3].w;
      float e4 = (pi == 0) ? xv[4].x : (pi == 1) ? xv[4].y : (pi == 2) ? xv[4].z : xv[4].w;
      float e5 = (pi == 0) ? xv[5].x : (pi == 1) ? xv[5].y : (pi == 2) ? xv[5].z : xv[5].w;
      float e6 = (pi == 0) ? xv[6].x : (pi == 1) ? xv[6].y : (pi == 2) ? xv[6].z : xv[6].w;
      float e7 = (pi == 0) ? xv[7].x : (pi == 1) ? xv[7].y : (pi == 2) ? xv[7].z : xv[7].w;
      unsigned r0 = (unsigned)f2bf(e0) | ((unsigned)f2bf(e1) << 16);
      unsigned r1 = (unsigned)f2bf(e2) | ((unsigned)f2bf(e3) << 16);
      unsigned r2 = (unsigned)f2bf(e4) | ((unsigned)f2bf(e5) << 16);
      unsigned r3 = (unsigned)f2bf(e6) | ((unsigned)f2bf(e7) << 16);
      int sp2 = px0 + pi;
      int blk = c8g ^ (sp2 & 7);
      *(uint4*)((char*)sa + sp2 * 128 + blk * 16) = make_uint4(r0, r1, r2, r3);
    }
    if (kc + 64 < Kpad) LOADP(kc + 64);   // T14: next-step loads fly under MFMA
    __syncthreads();
#pragma unroll
    for (int ks = 0; ks < 2; ++ks) {
      bf16x8 af[4], bfr[4];
#pragma unroll
      for (int i = 0; i < 4; ++i) {
        int pr = wm + i * 16 + (lane & 15);
        int blk = ((ks * 4 + (lane >> 4)) ^ (pr & 7));
        af[i] = *(const bf16x8*)((const char*)sa + pr * 128 + blk * 16);
      }
#pragma unroll
      for (int j = 0; j < 4; ++j)
        bfr[j] = ldfrag(wb + (size_t)(wn + j * 16) * Kpad + kc + ks * 32, Kpad, lane);
#pragma unroll
      for (int i = 0; i < 4; ++i)
#pragma unroll
        for (int j = 0; j < 4; ++j)
          acc[i][j] = __builtin_amdgcn_mfma_f32_16x16x32_bf16(af[i], bfr[j], acc[i][j], 0, 0, 0);
    }
  }
#undef LOADP
  int col = lane & 15, rq = lane >> 4;
  __hip_bfloat16* ob = outp + (size_t)b * PSTRIDE * 128;
#pragma unroll
  for (int j = 0; j < 4; ++j) {
    int d = wn + j * 16 + col;
    float s = g[d] * rsqrtf(var[d] + 1e-5f);
    float mm = mu[d], bb = be[d];
#pragma unroll
    for (int i = 0; i < 4; ++i) {
#pragma unroll
      for (int r = 0; r < 4; ++r) {
        int m = m0 + wm + i * 16 + rq * 4 + r;
        if (m < HW) {
          float y = (acc[i][j][r] - mm) * s + bb;
          ob[(size_t)m * 128 + d] = __float2bfloat16(fmaxf(y, 0.f));
        }
      }
    }
  }
}

// ---------------------------------------------------------------------------
// 2) q + kv GEMMs merged in one launch: y=0 -> q (from lid), y=1,2 -> kv
//    (from cam, N-block y-1). All K=128.
// ---------------------------------------------------------------------------
__global__ void __launch_bounds__(256) k_qkv_gemm(
    const __hip_bfloat16* __restrict__ lid_bf, const __hip_bfloat16* __restrict__ cam_bf,
    const __hip_bfloat16* __restrict__ wipb, const float* __restrict__ ipb,
    __hip_bfloat16* __restrict__ qc, __hip_bfloat16* __restrict__ kvb) {
  int yy = blockIdx.y;
  const __hip_bfloat16* A;
  const __hip_bfloat16* B;
  const float* bias;
  __hip_bfloat16* out;
  int ldout, n0;
  float oscale;
  if (yy == 0) {
    A = lid_bf; B = wipb; bias = ipb; out = qc; ldout = 128; n0 = 0; oscale = QSCALE;
  } else {
    A = cam_bf; B = wipb + 128 * 128; bias = ipb + 128; out = kvb;
    ldout = 256; n0 = (yy - 1) * 128; oscale = 1.0f;
  }
  int m0 = blockIdx.x * 128, b = blockIdx.z;
  int lane = threadIdx.x & 63, wid = threadIdx.x >> 6;
  int wm = (wid >> 1) * 64, wn = (wid & 1) * 64;
  const __hip_bfloat16* Ab = A + (size_t)b * PSTRIDE * 128;
  f32x4 acc[4][4] = {};
  for (int kc = 0; kc < 128; kc += 32) {
    bf16x8 af[4], bfr[4];
#pragma unroll
    for (int i = 0; i < 4; ++i)
      af[i] = ldfrag(Ab + (size_t)(m0 + wm + i * 16) * 128 + kc, 128, lane);
#pragma unroll
    for (int j = 0; j < 4; ++j)
      bfr[j] = ldfrag(B + (size_t)(n0 + wn + j * 16) * 128 + kc, 128, lane);
#pragma unroll
    for (int i = 0; i < 4; ++i)
#pragma unroll
      for (int j = 0; j < 4; ++j)
        acc[i][j] = __builtin_amdgcn_mfma_f32_16x16x32_bf16(af[i], bfr[j], acc[i][j], 0, 0, 0);
  }
  int col = lane & 15, rq = lane >> 4;
  __hip_bfloat16* ob = out + (size_t)b * PSTRIDE * ldout;
#pragma unroll
  for (int j = 0; j < 4; ++j) {
    int n = n0 + wn + j * 16 + col;
    float bs = bias[n];
#pragma unroll
    for (int i = 0; i < 4; ++i) {
#pragma unroll
      for (int r = 0; r < 4; ++r) {
        int m = m0 + wm + i * 16 + rq * 4 + r;
        if (m < HW) ob[(size_t)m * ldout + n] = __float2bfloat16((acc[i][j][r] + bs) * oscale);
      }
    }
  }
}

// ---------------------------------------------------------------------------
// 3) MFMA flash attention per (bn, head) — 16x16x16 MFMA, P stays in regs.
//    Also absorbs the fb-border zeroing (fbbuf disjoint from qc/kvb).
// ---------------------------------------------------------------------------
__global__ void __launch_bounds__(256) k_attn_mfma(
    const __hip_bfloat16* __restrict__ qc, const __hip_bfloat16* __restrict__ kvb,
    __hip_bfloat16* __restrict__ ctx, __hip_bfloat16* __restrict__ fbb) {
  __shared__ __align__(8) uint2 Kf[15 * 64];   // frag-major K: lane(g,q)=K[key q][d g*4..+3]
  __shared__ __align__(8) uint2 Vf[15 * 64];   // frag-major V^T: lane(g,q)=V^T[d q][key g*4..+3]
  int bn = blockIdx.x, hh = blockIdx.y;
  int b = bn / 144, rr = bn % 144, tby = rr / 12, tbx = rr % 12;
  int tid = threadIdx.x;
  int pbase = tby * 15 * WIMG + tbx * 15;
  const __hip_bfloat16* kvbase = kvb + (size_t)b * PSTRIDE * 256 + hh * 16;

  // ---- absorbed fb border zeroing (92*256 = 23552 items exactly) ----
  if (hh == 0 && bn < 92) {
    int idx = bn * 256 + tid;
    int zb = idx / (736 * 16);
    int r = idx % (736 * 16);
    int px = r >> 4, blk = r & 15;
    int row, col;
    if (px < 188)      { row = 0;            col = px; }
    else if (px < 376) { row = 181;          col = px - 188; }
    else if (px < 556) { row = px - 376 + 1; col = 0; }
    else               { row = px - 556 + 1; col = 181; }
    ((uint4*)(fbb + (size_t)zb * FBSZ + ((size_t)row * FBROW + col) * 128))[blk] =
        make_uint4(0u, 0u, 0u, 0u);
  }

  // ---- stage K and V^T into frag-major layout ----
  if (tid < 240) {
    int row = tid;
    int ck = row >> 4, q = row & 15;
    uint4 k0 = make_uint4(0, 0, 0, 0), k1 = k0, v0 = k0, v1 = k0;
    if (row < LTOK) {
      int p = pbase + (row / 15) * WIMG + (row % 15);
      const uint4* kp = (const uint4*)(kvbase + (size_t)p * 256);
      k0 = kp[0]; k1 = kp[1];
      v0 = kp[16]; v1 = kp[17];     // V at +128 elements
    }
    Kf[ck * 64 + q]      = make_uint2(k0.x, k0.y);
    Kf[ck * 64 + 16 + q] = make_uint2(k0.z, k0.w);
    Kf[ck * 64 + 32 + q] = make_uint2(k1.x, k1.y);
    Kf[ck * 64 + 48 + q] = make_uint2(k1.z, k1.w);
    unsigned short vv[16];
    *(uint4*)&vv[0] = v0;
    *(uint4*)&vv[8] = v1;
    int vg = q >> 2, vj = q & 3;
    unsigned short* vb = (unsigned short*)&Vf[ck * 64 + vg * 16];
#pragma unroll
    for (int d0 = 0; d0 < 16; ++d0) {
      int d = (d0 + q) & 15;
      vb[d * 4 + vj] = vv[d];
    }
  }
  __syncthreads();

  int lane = tid & 63, wid = tid >> 6;
  int g = lane >> 4, q15 = lane & 15;
  int wq0 = wid * 64;
  const uint2* KfB = Kf + lane;
  const uint2* VfB = Vf + lane;

  // Q fragments: lane(g,q15) = Q[query q15][d g*4..+3] — full dh, no padding
  bf16x4 qf[4];
#pragma unroll
  for (int i = 0; i < 4; ++i) {
    int q = wq0 + i * 16 + q15;
    int qq = q < LTOK ? q : 0;
    int p = pbase + (qq / 15) * WIMG + (qq % 15);
    U8B u;
    u.u = *(const uint2*)(qc + ((size_t)b * PSTRIDE + p) * 128 + hh * 16 + g * 4);
    qf[i] = u.v;
  }

  float ls[4] = {0.f, 0.f, 0.f, 0.f};
  f32x4 oac[4] = {};
#pragma unroll 1
  for (int ck = 0; ck < 15; ++ck) {
    U8B ku; ku.u = KfB[ck * 64];
    U8B vu; vu.u = VfB[ck * 64];
    bf16x4 kf = ku.v, vf = vu.v;
#pragma unroll
    for (int i = 0; i < 4; ++i) {
      f32x4 st = {0.f, 0.f, 0.f, 0.f};
      asm("v_mfma_f32_16x16x16_bf16 %0, %1, %2, %0" : "+v"(st) : "v"(kf), "v"(qf[i]));
      float p0 = exp2f(st[0]);
      float p1 = exp2f(st[1]);
      float p2 = exp2f(st[2]);
      float p3 = exp2f(st[3]);
      if (ck == 14) {                  // keys 224..239: only key 224 (g=0,r=0) valid
        if (g) p0 = 0.f;
        p1 = 0.f; p2 = 0.f; p3 = 0.f;
      }
      ls[i] += (p0 + p1) + (p2 + p3);
      U8B pu;
      pu.u = make_uint2((unsigned)f2bf(p0) | ((unsigned)f2bf(p1) << 16),
                        (unsigned)f2bf(p2) | ((unsigned)f2bf(p3) << 16));
      asm("v_mfma_f32_16x16x16_bf16 %0, %1, %2, %0" : "+v"(oac[i]) : "v"(vf), "v"(pu.v));
    }
  }
#pragma unroll
  for (int i = 0; i < 4; ++i) {
    ls[i] += __shfl_xor(ls[i], 16);
    ls[i] += __shfl_xor(ls[i], 32);
  }

  // ---- epilogue: normalize and store (lane owns ctx[q][hh*16 + g*4 .. +3]) ----
  __hip_bfloat16* cb = ctx + (size_t)b * PSTRIDE * 128 + hh * 16;
#pragma unroll
  for (int i = 0; i < 4; ++i) {
    float inv = 1.f / ls[i];
    int qo = wq0 + i * 16 + q15;
    if (qo < LTOK) {
      unsigned lo = (unsigned)f2bf(oac[i][0] * inv) | ((unsigned)f2bf(oac[i][1] * inv) << 16);
      unsigned hi = (unsigned)f2bf(oac[i][2] * inv) | ((unsigned)f2bf(oac[i][3] * inv) << 16);
      int p = pbase + (qo / 15) * WIMG + (qo % 15);
      *(uint2*)(cb + (size_t)p * 128 + g * 4) = make_uint2(lo, hi);
    }
  }
}

// ---------------------------------------------------------------------------
// 4) out-proj MFMA GEMM + bias + residual -> padded fb bf16
// ---------------------------------------------------------------------------
__global__ void __launch_bounds__(256) k_outproj_mfma(
    const __hip_bfloat16* __restrict__ ctx, const __hip_bfloat16* __restrict__ wob,
    const float* __restrict__ opb, const __hip_bfloat16* __restrict__ lidb,
    __hip_bfloat16* __restrict__ fb) {
  int m0 = blockIdx.x * 128, b = blockIdx.z;
  int lane = threadIdx.x & 63, wid = threadIdx.x >> 6;
  int wm = (wid >> 1) * 64, wn = (wid & 1) * 64;
  const __hip_bfloat16* Ab = ctx + (size_t)b * PSTRIDE * 128;
  f32x4 acc[4][4] = {};
  for (int kc = 0; kc < 128; kc += 32) {
    bf16x8 af[4], bfr[4];
#pragma unroll
    for (int i = 0; i < 4; ++i)
      af[i] = ldfrag(Ab + (size_t)(m0 + wm + i * 16) * 128 + kc, 128, lane);
#pragma unroll
    for (int j = 0; j < 4; ++j)
      bfr[j] = ldfrag(wob + (size_t)(wn + j * 16) * 128 + kc, 128, lane);
#pragma unroll
    for (int i = 0; i < 4; ++i)
#pragma unroll
      for (int j = 0; j < 4; ++j)
        acc[i][j] = __builtin_amdgcn_mfma_f32_16x16x32_bf16(af[i], bfr[j], acc[i][j], 0, 0, 0);
  }
  int col = lane & 15, rq = lane >> 4;
  const __hip_bfloat16* lb = lidb + (size_t)b * PSTRIDE * 128;
  __hip_bfloat16* fbp = fb + (size_t)b * FBSZ;
#pragma unroll
  for (int j = 0; j < 4; ++j) {
    int n = wn + j * 16 + col;
    float bs = opb[n];
#pragma unroll
    for (int i = 0; i < 4; ++i) {
#pragma unroll
      for (int r = 0; r < 4; ++r) {
        int m = m0 + wm + i * 16 + rq * 4 + r;
        if (m < HW) {
          float v = acc[i][j][r] + bs + __bfloat162float(lb[(size_t)m * 128 + n]);
          int hhh = m / WIMG, www = m % WIMG;
          fbp[((size_t)(hhh + 1) * FBROW + (www + 1)) * 128 + n] = __float2bfloat16(v);
        }
      }
    }
  }
}

// ---------------------------------------------------------------------------
// 5) 3x3 conv 128->256 + BN + ReLU: 2 rows x 60 px x 256 oc per block,
//    ic-halved LDS A staging (row stride 63), 3-deep B register prefetch.
//    NO min-waves bound (r14/r20 lesson: (512,4) caps VGPR at 64 -> spill).
// ---------------------------------------------------------------------------
__global__ void __launch_bounds__(512) k_conv_mfma(
    const __hip_bfloat16* __restrict__ fb, const __hip_bfloat16* __restrict__ wcb,
    const float* __restrict__ g, const float* __restrict__ be,
    const float* __restrict__ mu, const float* __restrict__ var,
    float* __restrict__ out) {
  __shared__ __align__(16) uint4 Asm[32 * 63];   // [dy(4)*8+kgrp8][px], row stride 63
  int bx = blockIdx.x;                 // 0..269: hpair*3 + strip
  int hp = bx / 3, strip = bx % 3;
  int h0 = hp * 2;                     // output rows h0, h0+1
  int w0 = strip * 60;
  int b = blockIdx.z;
  int tid = threadIdx.x, lane = tid & 63, wid = tid >> 6;   // wid 0..7
  int q15 = lane & 15, kg = lane >> 4;
  int wpx = (wid & 1) * 32;            // pixel half
  int ocq = wid >> 1;                  // oc quarter (0..3)
  const __hip_bfloat16* fbb = fb + (size_t)b * FBSZ;
  const __hip_bfloat16* Bw = wcb + (size_t)(ocq * 4) * 18432 + lane * 8;

#define STAGEA(half)                                                           \
  {                                                                            \
    _Pragma("unroll") for (int it = 0; it < 4; ++it) {                         \
      int slot = it * 512 + tid;                                               \
      if (slot < 1984) {                                                       \
        int px = slot % 62;                                                    \
        int rowk = slot / 62;          /* dy*8 + k8 */                         \
        int dy = rowk >> 3, k8 = rowk & 7;                                     \
        Asm[rowk * 63 + px] = *(const uint4*)(fbb + ((size_t)(h0 + dy) * FBROW + (w0 + px)) * 128 + ((half) * 8 + k8) * 8); \
      }                                                                        \
    }                                                                          \
  }

// global step s (0..35): half = s/18, tap = (s%18)/2, ch2 = s&1
#define LOADB(dst, s)                                                          \
  {                                                                            \
    int half_ = (s) / 18, rem_ = (s) % 18, tap_ = rem_ / 2, ch2_ = rem_ & 1;   \
    int chunk_ = half_ * 2 + ch2_;                                             \
    _Pragma("unroll") for (int j = 0; j < 4; ++j)                              \
        dst[j] = *(const bf16x8*)(Bw + (size_t)j * 18432 + tap_ * 2048 + chunk_ * 512); \
  }

#define LOADBG(dst, s)                                                         \
  { if ((s) < 36) LOADB(dst, s); }

#define STEP(s, bp)                                                            \
  {                                                                            \
    int rem_ = (s) % 18, tap_ = rem_ / 2, ch2_ = rem_ & 1;                     \
    int dy_ = tap_ / 3, dx_ = tap_ % 3;                                        \
    bf16x8 af[2][2];                                                           \
    _Pragma("unroll") for (int r = 0; r < 2; ++r) {                            \
      int rowk_ = ((dy_ + r) * 8 + ch2_ * 4 + kg) * 63;                        \
      _Pragma("unroll") for (int i = 0; i < 2; ++i)                            \
          af[r][i] = *(const bf16x8*)&Asm[rowk_ + wpx + i * 16 + q15 + dx_];   \
    }                                                                          \
    _Pragma("unroll") for (int r = 0; r < 2; ++r)                              \
        _Pragma("unroll") for (int i = 0; i < 2; ++i)                          \
            _Pragma("unroll") for (int j = 0; j < 4; ++j)                      \
                acc[r][i][j] = __builtin_amdgcn_mfma_f32_16x16x32_bf16(af[r][i], bp[j], acc[r][i][j], 0, 0, 0); \
  }

// triad: steps s, s+1, s+2 on bp0..bp2, prefetching s+3..s+5 (guarded)
#define TRIAD(s)                                                               \
  STEP(s, bp0); LOADBG(bp0, (s) + 3);                                          \
  STEP((s) + 1, bp1); LOADBG(bp1, (s) + 4);                                    \
  STEP((s) + 2, bp2); LOADBG(bp2, (s) + 5);

  bf16x8 bp0[4], bp1[4], bp2[4];
  STAGEA(0);
  LOADB(bp0, 0);
  LOADB(bp1, 1);
  LOADB(bp2, 2);
  __syncthreads();

  f32x4 acc[2][2][4] = {};

  TRIAD(0); TRIAD(3); TRIAD(6); TRIAD(9); TRIAD(12); TRIAD(15);
  __syncthreads();              // all reads of half-0 Asm complete
  STAGEA(1);
  __syncthreads();
  TRIAD(18); TRIAD(21); TRIAD(24); TRIAD(27); TRIAD(30); TRIAD(33);
#undef TRIAD
#undef STEP
#undef LOADB
#undef LOADBG
#undef STAGEA

  int ocbase = ocq * 64;
#pragma unroll
  for (int j = 0; j < 4; ++j) {
    int oc = ocbase + j * 16 + q15;
    float s = g[oc] * rsqrtf(var[oc] + 1e-5f);
    float mm = mu[oc], bb = be[oc];
#pragma unroll
    for (int r = 0; r < 2; ++r) {
#pragma unroll
      for (int i = 0; i < 2; ++i) {
        int pxb = wpx + i * 16 + kg * 4;
        if (pxb < 60) {
          float4 o4;
          o4.x = fmaxf((acc[r][i][j][0] - mm) * s + bb, 0.f);
          o4.y = fmaxf((acc[r][i][j][1] - mm) * s + bb, 0.f);
          o4.z = fmaxf((acc[r][i][j][2] - mm) * s + bb, 0.f);
          o4.w = fmaxf((acc[r][i][j][3] - mm) * s + bb, 0.f);
          *(float4*)(&out[(size_t)(b * 256 + oc) * HW + (h0 + r) * WIMG + w0 + pxb]) = o4;
        }
      }
    }
  }
}

// ---------------------------------------------------------------------------
extern "C" void kernel_launch(void* const* d_in, const int* in_sizes, int n_in,
                              void* d_out, int out_size, void* d_ws, size_t ws_size,
                              hipStream_t stream) {
  const float* camera = (const float*)d_in[0];
  const float* lidar  = (const float*)d_in[1];
  const float* cam_w  = (const float*)d_in[2];
  const float* cam_g  = (const float*)d_in[3];
  const float* cam_b  = (const float*)d_in[4];
  const float* cam_m  = (const float*)d_in[5];
  const float* cam_v  = (const float*)d_in[6];
  const float* lid_w  = (const float*)d_in[7];
  const float* lid_g  = (const float*)d_in[8];
  const float* lid_b  = (const float*)d_in[9];
  const float* lid_m  = (const float*)d_in[10];
  const float* lid_v  = (const float*)d_in[11];
  const float* ipw    = (const float*)d_in[12];
  const float* ipb    = (const float*)d_in[13];
  const float* opw    = (const float*)d_in[14];
  const float* opb    = (const float*)d_in[15];
  const float* ocw    = (const float*)d_in[16];
  const float* ocg    = (const float*)d_in[17];
  const float* ocb    = (const float*)d_in[18];
  const float* ocm    = (const float*)d_in[19];
  const float* ocv    = (const float*)d_in[20];

  __hip_bfloat16* ws = (__hip_bfloat16*)d_ws;
  const size_t NP = (size_t)2 * PSTRIDE * 128;
  __hip_bfloat16* cam_bf = ws;                    // aliased by fb later
  __hip_bfloat16* lid_bf = ws + NP;
  __hip_bfloat16* qc     = ws + 2 * NP;           // q, then ctx (in-place)
  __hip_bfloat16* kvb    = ws + 3 * NP;           // [p][256], 2*NP elements
  __hip_bfloat16* wipb   = ws + 5 * NP;           // 384*128
  __hip_bfloat16* wob    = wipb + 384 * 128;      // 128*128
  __hip_bfloat16* wcb    = wob + 128 * 128;       // 256*9*128 (frag-major)
  __hip_bfloat16* wcamb  = wcb + 256 * 9 * 128;   // 128*128 (Kpad=128)
  __hip_bfloat16* wlidb  = wcamb + 128 * 128;     // 128*256
  __hip_bfloat16* fbbuf  = cam_bf;

  dim3 blk(256);
  // fused weight prep (409600 items)
  hipLaunchKernelGGL(k_prep_all, dim3(1600), blk, 0, stream,
                     ipw, opw, ocw, cam_w, lid_w, wipb, wob, wcb, wcamb, wlidb);
  // projections (cam + lid merged, fully parallel) -> pixel-major bf16
  hipLaunchKernelGGL(k_proj_mfma, dim3(254, 2, 2), blk, 0, stream,
                     camera, lidar, wcamb, wlidb,
                     cam_g, cam_b, cam_m, cam_v,
                     lid_g, lid_b, lid_m, lid_v,
                     cam_bf, lid_bf);
  // q + kv GEMMs merged (q scaled by log2(e)/4 for exp2-domain softmax)
  hipLaunchKernelGGL(k_qkv_gemm, dim3(254, 3, 2), blk, 0, stream,
                     lid_bf, cam_bf, wipb, ipb, qc, kvb);
  // attention (qc -> qc in place) + absorbed fb border zeroing
  hipLaunchKernelGGL(k_attn_mfma, dim3(288, 8), blk, 0, stream, qc, kvb, qc, fbbuf);
  // out-proj + residual -> fb
  hipLaunchKernelGGL(k_outproj_mfma, dim3(254, 1, 2), blk, 0, stream,
                     qc, wob, opb, lid_bf, fbbuf);
  // conv + BN + ReLU  (2 rows x 60 px x 256 oc, ic-halved LDS, 3-deep B)
  hipLaunchKernelGGL(k_conv_mfma, dim3(270, 1, 2), dim3(512), 0, stream,
                     fbbuf, wcb, ocg, ocb, ocm, ocv, (float*)d_out);
}